// Round 7
// baseline (247.428 us; speedup 1.0000x reference)
//
#include <hip/hip_runtime.h>
#include <stdint.h>

#define BTOK 32768
#define DIN 256
#define DHID 512
#define DOUT 256
#define NEXP 16
#define BM 128
#define CH 32
#define NCH 16
#define SLOTS 96

typedef __attribute__((ext_vector_type(8))) short bf16x8;
typedef __attribute__((ext_vector_type(4))) float f32x4;

__device__ __forceinline__ unsigned short f2bf(float f){
  unsigned u = __builtin_bit_cast(unsigned, f);
  u = u + 0x7FFFu + ((u >> 16) & 1u);      // RNE, finite inputs only
  return (unsigned short)(u >> 16);
}
__device__ __forceinline__ float bf2f(unsigned short h){
  return __builtin_bit_cast(float, (unsigned)h << 16);
}
__device__ __forceinline__ void gload16(const void* g, void* l){
  __builtin_amdgcn_global_load_lds((const __attribute__((address_space(1))) unsigned int*)g,
                                   (__attribute__((address_space(3))) unsigned int*)l, 16, 0, 0);
}

// ---------------- W1 transpose + cvt: src[e][256 i][512 h] -> dst[e][512 h][256 i]
__global__ __launch_bounds__(256) void transpose_cvt(const float* __restrict__ src,
                                                     unsigned short* __restrict__ dst,
                                                     int R, int C){
  __shared__ float t[32][33];
  int e = blockIdx.z, r0 = blockIdx.y * 32, c0 = blockIdx.x * 32;
  int lx = threadIdx.x & 31, ly = threadIdx.x >> 5;
  const float* s = src + (size_t)e * R * C;
  unsigned short* d = dst + (size_t)e * R * C;
#pragma unroll
  for (int i = 0; i < 4; i++){ int r = ly + i * 8; t[r][lx] = s[(size_t)(r0 + r) * C + c0 + lx]; }
  __syncthreads();
#pragma unroll
  for (int i = 0; i < 4; i++){ int r = ly + i * 8; d[(size_t)(c0 + r) * R + r0 + lx] = f2bf(t[lx][r]); }
}

// ---------------- W2 transpose + cvt into chunk-major: src[e][512 h][256 o] -> dst[e][16][256 o][32 h]
__global__ __launch_bounds__(256) void transpose_cvt_w2(const float* __restrict__ src,
                                                        unsigned short* __restrict__ dst){
  __shared__ float t[32][33];
  int e = blockIdx.z, r0 = blockIdx.y * 32, c0 = blockIdx.x * 32;   // r0 over h, c0 over o
  int lx = threadIdx.x & 31, ly = threadIdx.x >> 5;
  const float* s = src + (size_t)e * DHID * DOUT;
  unsigned short* d = dst + (size_t)e * DHID * DOUT + (r0 >> 5) * (DOUT * CH);
#pragma unroll
  for (int i = 0; i < 4; i++){ int r = ly + i * 8; t[r][lx] = s[(size_t)(r0 + r) * DOUT + c0 + lx]; }
  __syncthreads();
#pragma unroll
  for (int i = 0; i < 4; i++){ int rr = ly + i * 8; d[(size_t)(c0 + rr) * CH + lx] = f2bf(t[lx][rr]); }
}

// ---------------- gating: 512 blocks x 64 tokens; LDS-aggregated histogram
__global__ __launch_bounds__(256) void gating_kernel(const float* __restrict__ x,
                                                     const float* __restrict__ Wg,
                                                     const float* __restrict__ bg,
                                                     unsigned short* __restrict__ x_bf,
                                                     int* __restrict__ top_idx,
                                                     float* __restrict__ top_w,
                                                     int* __restrict__ counts){
  __shared__ float WgT[16][256];
  __shared__ int hist[16];
  int tid = threadIdx.x;
#pragma unroll
  for (int j = 0; j < 4; j++){
    float4 wv = *(const float4*)(Wg + tid * 16 + j * 4);
    WgT[j * 4 + 0][tid] = wv.x; WgT[j * 4 + 1][tid] = wv.y;
    WgT[j * 4 + 2][tid] = wv.z; WgT[j * 4 + 3][tid] = wv.w;
  }
  if (tid < 16) hist[tid] = 0;
  __syncthreads();
  int wid = tid >> 6, lane = tid & 63;

  for (int t = 0; t < 16; t++){
    int tok = blockIdx.x * 64 + wid * 16 + t;
    const float4 xv = *(const float4*)(x + (size_t)tok * DIN + lane * 4);
    ushort4 xb; xb.x = f2bf(xv.x); xb.y = f2bf(xv.y); xb.z = f2bf(xv.z); xb.w = f2bf(xv.w);
    *(ushort4*)(x_bf + (size_t)tok * DIN + lane * 4) = xb;
    float logit[16];
#pragma unroll
    for (int e = 0; e < 16; e++){
      const float4 wv = *(const float4*)(&WgT[e][lane * 4]);
      float v = xv.x * wv.x + xv.y * wv.y + xv.z * wv.z + xv.w * wv.w;
#pragma unroll
      for (int off = 32; off; off >>= 1) v += __shfl_xor(v, off, 64);
      logit[e] = v + bg[e];
    }
    if (lane == 0){
      int i1 = 0; float v1 = logit[0];
#pragma unroll
      for (int e = 1; e < 16; e++) if (logit[e] > v1){ v1 = logit[e]; i1 = e; }
      int i2 = -1; float v2 = -3.4e38f;
#pragma unroll
      for (int e = 0; e < 16; e++) if (e != i1 && logit[e] > v2){ v2 = logit[e]; i2 = e; }
      float tt = expf(v2 - v1);
      float w1 = 1.0f / (1.0f + tt);
      float w2 = tt / (1.0f + tt);
      top_idx[tok * 2] = i1; top_idx[tok * 2 + 1] = i2;
      top_w[tok * 2] = w1;  top_w[tok * 2 + 1] = w2;
      atomicAdd(&hist[i1], 1); atomicAdd(&hist[i2], 1);
    }
  }
  __syncthreads();
  if (tid < 16) atomicAdd(&counts[tid], hist[tid]);
}

// ---------------- prefix sum + XCD-affine block map (one wave)
__global__ void prefix_kernel(const int* __restrict__ counts, int* __restrict__ offsets,
                              int* __restrict__ cursor, int* __restrict__ bm_e,
                              int* __restrict__ bm_start, int* __restrict__ bm_end){
  int lane = threadIdx.x & 63;
  int c = (lane < 16) ? counts[lane] : 0;
  int s = c;
#pragma unroll
  for (int off = 1; off < 16; off <<= 1){ int o = __shfl_up(s, off, 64); if (lane >= off) s += o; }
  int start = s - c;
  if (lane < 16){ offsets[lane] = start; cursor[lane] = start; }
  int nb = (c + BM - 1) >> 7;
  int nb_partner = __shfl(nb, lane ^ 8, 64);
  if (lane < 8){
    int filled = nb + nb_partner;
    if (filled > SLOTS) filled = SLOTS;
    for (int i = filled; i < SLOTS; i++) bm_e[lane * SLOTS + i] = -1;
  }
  if (lane < 16){
    int sbase = (lane < 8) ? 0 : nb_partner;
    int xcd = lane & 7;
    for (int b = 0; b < nb; b++){
      int idx = xcd * SLOTS + sbase + b;
      if (sbase + b < SLOTS){
        bm_e[idx] = lane; bm_start[idx] = start + b * BM; bm_end[idx] = start + c;
      }
    }
  }
}

// ---------------- scatter: block-aggregated chunk reservation, LDS ranks
__global__ __launch_bounds__(256) void scatter_kernel(const int* __restrict__ top_idx,
                                                      const float* __restrict__ top_w,
                                                      int* __restrict__ cursor,
                                                      int* __restrict__ pair_tok,
                                                      float* __restrict__ pair_w,
                                                      int* __restrict__ pair_slot){
  __shared__ int hist[16], base[16], rank[16];
  int tid = threadIdx.x;
  if (tid < 16){ hist[tid] = 0; rank[tid] = 0; }
  __syncthreads();
  int t = blockIdx.x * 256 + tid;
  int e0 = top_idx[t * 2], e1 = top_idx[t * 2 + 1];
  float w0 = top_w[t * 2], w1 = top_w[t * 2 + 1];
  atomicAdd(&hist[e0], 1); atomicAdd(&hist[e1], 1);
  __syncthreads();
  if (tid < 16) base[tid] = atomicAdd(&cursor[tid], hist[tid]);
  __syncthreads();
  int r0 = atomicAdd(&rank[e0], 1);
  int p0 = base[e0] + r0;
  pair_tok[p0] = t; pair_w[p0] = w0; pair_slot[t * 2] = p0;
  int r1 = atomicAdd(&rank[e1], 1);
  int p1 = base[e1] + r1;
  pair_tok[p1] = t; pair_w[p1] = w1; pair_slot[t * 2 + 1] = p1;
}

// ---------------- fused 2-layer expert MLP: 128 pairs/block, 4 waves, M=32/wave
// Each W-fragment ds_read feeds 2 MFMAs (2 m-tiles) -> LDS-read/pair halved.
// Double-buffered global_load_lds staging (stage c+1 before compute c,
// 1 barrier/chunk); h wave-private; 72KB LDS -> 2 blocks/CU.
__global__ __launch_bounds__(256, 2) void moe_gemm_kernel(
    const unsigned short* __restrict__ x_bf,   // [B][256]
    const unsigned short* __restrict__ W1t,    // [E][512 h][256 i]
    const unsigned short* __restrict__ W2c,    // [E][16 c][256 o][32 h]
    const float* __restrict__ b1,              // [E][512]
    const float* __restrict__ b2,              // [E][256]
    const int* __restrict__ pair_tok, const float* __restrict__ pair_w,
    const int* __restrict__ bm_e, const int* __restrict__ bm_start,
    const int* __restrict__ bm_end,
    unsigned short* __restrict__ ypair){       // [65536][256] bf16
  int xcd = blockIdx.x & 7, slot = blockIdx.x >> 3;
  int bmi = xcd * SLOTS + slot;
  int e = bm_e[bmi];
  if (e < 0) return;
  int rs = bm_start[bmi], re = bm_end[bmi];

  __shared__ unsigned short w1s[2][CH * 256];   // 2x16KB [h row][i], 512B rows, XOR(bits4-6)
  __shared__ unsigned short w2s[2][256 * CH];   // 2x16KB [o row][h], row-pair 128B XOR
  __shared__ unsigned short hsm[4][CH * CH];    // 8KB, per-wave [m 32][h 32], row-pair 128B XOR

  int tid = threadIdx.x, wid = tid >> 6, lane = tid & 63, lr = lane & 15, lh = lane >> 4;
  char* hsb = (char*)hsm[wid];
  const char* gW1 = (const char*)(W1t + (size_t)e * DHID * DIN);
  const char* gW2 = (const char*)(W2c + (size_t)e * DOUT * DHID);

  // ---- per-lane loop-invariant staging source offsets (pre-swizzled)
  int o1[4], o2[4];
#pragma unroll
  for (int k = 0; k < 4; k++){
    int g = k * 256 + tid;              // physical 16B granule index
    int r = g >> 5;                     // w1: row (512B = 32 granules)
    o1[k] = r * 512 + ((g & 31) ^ (r & 7)) * 16;
    int p = g >> 3;                     // w2: row-pair (128B = 8 granules)
    int q = (g & 7) ^ (p & 7);
    int n = p * 2 + (q >> 2), sgr = q & 3;
    o2[k] = n * 64 + sgr * 16;
  }

  // ---- x rows (2 per lane: m=0,1) -> registers, once per block
  bf16x8 xr[2][8];
#pragma unroll
  for (int m = 0; m < 2; m++){
    int g0 = rs + 32 * wid + m * 16 + lr;
    int gc = g0 < re ? g0 : (re - 1);
    int tok = pair_tok[gc];
    const unsigned short* xrow = x_bf + (size_t)tok * DIN + lh * 8;
#pragma unroll
    for (int ks = 0; ks < 8; ks++) xr[m][ks] = *(const bf16x8*)(xrow + ks * 32);
  }

#define STAGE(c, sl) {                                                    \
    const char* s1 = gW1 + (size_t)(c) * 16384;                           \
    const char* s2 = gW2 + (size_t)(c) * 16384;                           \
    char* d1 = (char*)w1s[sl]; char* d2 = (char*)w2s[sl];                 \
    _Pragma("unroll")                                                     \
    for (int k = 0; k < 4; k++){                                          \
      gload16(s1 + o1[k], d1 + k * 4096 + wid * 1024);                    \
      gload16(s2 + o2[k], d2 + k * 4096 + wid * 1024);                    \
    } }

  f32x4 acc[2][16];
#pragma unroll
  for (int m = 0; m < 2; m++)
#pragma unroll
    for (int i = 0; i < 16; i++) acc[m][i] = (f32x4){0.f, 0.f, 0.f, 0.f};

  STAGE(0, 0);
  __syncthreads();                       // chunk-0 staged (vmcnt drained)

  for (int c = 0; c < NCH; c++){
    int sl = c & 1;
    if (c + 1 < NCH) STAGE(c + 1, sl ^ 1);   // in flight during compute

    // ---- phase A: h[2x16 tok][32 hid] = x @ W1c ; each B-read feeds 2 MFMAs
    const char* w1b = (const char*)w1s[sl];
    f32x4 hacc[2][2];
#pragma unroll
    for (int m = 0; m < 2; m++){ hacc[m][0] = (f32x4){0,0,0,0}; hacc[m][1] = (f32x4){0,0,0,0}; }
#pragma unroll
    for (int ks = 0; ks < 8; ks++){
#pragma unroll
      for (int nt = 0; nt < 2; nt++){
        int row = nt * 16 + lr;
        bf16x8 b = *(const bf16x8*)(w1b + ((row * 512 + ks * 64 + lh * 16) ^ ((row & 7) << 4)));
        hacc[0][nt] = __builtin_amdgcn_mfma_f32_16x16x32_bf16(xr[0][ks], b, hacc[0][nt], 0, 0, 0);
        hacc[1][nt] = __builtin_amdgcn_mfma_f32_16x16x32_bf16(xr[1][ks], b, hacc[1][nt], 0, 0, 0);
      }
    }

    // ---- relu(h+b1) -> wave-private hs (row-pair XOR layout, rows 0..31)
#pragma unroll
    for (int nt = 0; nt < 2; nt++){
      float b1v = b1[e * DHID + c * CH + nt * 16 + lr];
#pragma unroll
      for (int m = 0; m < 2; m++)
#pragma unroll
        for (int r = 0; r < 4; r++){
          int mm = m * 16 + lh * 4 + r;
          int bb = (nt * 16 + lr) * 2;
          float v = fmaxf(hacc[m][nt][r] + b1v, 0.f);
          int adr = (mm >> 1) * 128 + ((((mm & 1) << 6) + bb) ^ (((mm >> 1) & 7) << 4));
          *(unsigned short*)(hsb + adr) = f2bf(v);
        }
    }

    // ---- phase B: y[2x16 tok][256 out] += h @ W2c ; each B-read feeds 2 MFMAs
    bf16x8 ha[2];
#pragma unroll
    for (int m = 0; m < 2; m++){
      int mm = m * 16 + lr;
      int hadr = (mm >> 1) * 128 + ((((mm & 1) << 6) + (lh << 4)) ^ (((mm >> 1) & 7) << 4));
      ha[m] = *(const bf16x8*)(hsb + hadr);
    }
    const char* w2b = (const char*)w2s[sl];
#pragma unroll
    for (int nt = 0; nt < 16; nt++){
      int n = nt * 16 + lr;
      int adr = (n >> 1) * 128 + ((((n & 1) << 6) + (lh << 4)) ^ (((n >> 1) & 7) << 4));
      bf16x8 b = *(const bf16x8*)(w2b + adr);
      acc[0][nt] = __builtin_amdgcn_mfma_f32_16x16x32_bf16(ha[0], b, acc[0][nt], 0, 0, 0);
      acc[1][nt] = __builtin_amdgcn_mfma_f32_16x16x32_bf16(ha[1], b, acc[1][nt], 0, 0, 0);
    }
    __syncthreads();   // staged chunk c+1 ready; reads of buf sl complete
  }

  // ---- epilogue: fold gate weight + b2, store per-pair bf16 rows
#pragma unroll
  for (int m = 0; m < 2; m++){
    float wrow[4]; int grow[4];
#pragma unroll
    for (int r = 0; r < 4; r++){
      int gg = rs + 32 * wid + m * 16 + lh * 4 + r;
      grow[r] = gg;
      wrow[r] = (gg < re) ? pair_w[gg] : 0.f;
    }
#pragma unroll
    for (int nt = 0; nt < 16; nt++){
      int col = nt * 16 + lr;
      float b2v = b2[e * DOUT + col];
#pragma unroll
      for (int r = 0; r < 4; r++){
        if (grow[r] < re)
          ypair[(size_t)grow[r] * DOUT + col] = f2bf(wrow[r] * (acc[m][nt][r] + b2v));
      }
    }
  }
#undef STAGE
}

// ---------------- combine two pair rows per token
__global__ __launch_bounds__(256) void combine_kernel(const unsigned short* __restrict__ yp,
                                                      const int* __restrict__ pair_slot,
                                                      float* __restrict__ out){
  int idx = blockIdx.x * 256 + threadIdx.x;
  int t = idx >> 6;
  int c4 = (idx & 63) << 2;
  int s0 = pair_slot[t * 2], s1 = pair_slot[t * 2 + 1];
  ushort4 a = *(const ushort4*)(yp + (size_t)s0 * DOUT + c4);
  ushort4 b = *(const ushort4*)(yp + (size_t)s1 * DOUT + c4);
  float4 o;
  o.x = bf2f(a.x) + bf2f(b.x);
  o.y = bf2f(a.y) + bf2f(b.y);
  o.z = bf2f(a.z) + bf2f(b.z);
  o.w = bf2f(a.w) + bf2f(b.w);
  *(float4*)(out + (size_t)t * DOUT + c4) = o;
}

extern "C" void kernel_launch(void* const* d_in, const int* in_sizes, int n_in,
                              void* d_out, int out_size, void* d_ws, size_t ws_size,
                              hipStream_t stream){
  (void)in_sizes; (void)n_in; (void)out_size; (void)ws_size;
  const float* x  = (const float*)d_in[0];
  const float* Wg = (const float*)d_in[1];
  const float* bg = (const float*)d_in[2];
  const float* W1 = (const float*)d_in[3];
  const float* b1 = (const float*)d_in[4];
  const float* W2 = (const float*)d_in[5];
  const float* b2 = (const float*)d_in[6];
  float* out = (float*)d_out;
  char* ws = (char*)d_ws;

  unsigned short* x_bf  = (unsigned short*)(ws);                 // 16,777,216
  unsigned short* W1t   = (unsigned short*)(ws + 16777216);      //  4,194,304
  unsigned short* W2ck  = (unsigned short*)(ws + 20971520);      //  4,194,304
  unsigned short* ypair = (unsigned short*)(ws + 25165824);      // 33,554,432
  int*   top_idx  = (int*)  (ws + 58720256);
  float* top_w    = (float*)(ws + 58982400);
  int*   pair_tok = (int*)  (ws + 59244544);
  float* pair_w   = (float*)(ws + 59506688);
  int*   pair_slot= (int*)  (ws + 59768832);
  int*   counts   = (int*)  (ws + 60030976);
  int*   offsets  = (int*)  (ws + 60031040);
  int*   cursor   = (int*)  (ws + 60031104);
  int*   bm_e     = (int*)  (ws + 60031232);   // 768 ints
  int*   bm_start = (int*)  (ws + 60036608);   // 768 ints
  int*   bm_end   = (int*)  (ws + 60041984);   // 768 ints

  hipMemsetAsync(counts, 0, 64, stream);
  transpose_cvt<<<dim3(16, 8, 16), 256, 0, stream>>>(W1, W1t, 256, 512);
  transpose_cvt_w2<<<dim3(8, 16, 16), 256, 0, stream>>>(W2, W2ck);
  gating_kernel<<<512, 256, 0, stream>>>(x, Wg, bg, x_bf, top_idx, top_w, counts);
  prefix_kernel<<<1, 64, 0, stream>>>(counts, offsets, cursor, bm_e, bm_start, bm_end);
  scatter_kernel<<<128, 256, 0, stream>>>(top_idx, top_w, cursor, pair_tok, pair_w, pair_slot);
  moe_gemm_kernel<<<8 * SLOTS, 256, 0, stream>>>(x_bf, W1t, W2ck, b1, b2, pair_tok, pair_w,
                                                 bm_e, bm_start, bm_end, ypair);
  combine_kernel<<<8192, 256, 0, stream>>>(ypair, pair_slot, out);
}

// Round 8
// 180.587 us; speedup vs baseline: 1.3701x; 1.3701x over previous
//
#include <hip/hip_runtime.h>
#include <stdint.h>

#define BTOK 32768
#define DIN 256
#define DHID 512
#define DOUT 256
#define NEXP 16
#define BM 128
#define CH 32
#define NCH 16
#define SLOTS 96

typedef __attribute__((ext_vector_type(8))) short bf16x8;
typedef __attribute__((ext_vector_type(4))) float f32x4;

__device__ __forceinline__ unsigned short f2bf(float f){
  unsigned u = __builtin_bit_cast(unsigned, f);
  u = u + 0x7FFFu + ((u >> 16) & 1u);      // RNE, finite inputs only
  return (unsigned short)(u >> 16);
}
__device__ __forceinline__ float bf2f(unsigned short h){
  return __builtin_bit_cast(float, (unsigned)h << 16);
}
__device__ __forceinline__ void gload16(const void* g, void* l){
  __builtin_amdgcn_global_load_lds((const __attribute__((address_space(1))) unsigned int*)g,
                                   (__attribute__((address_space(3))) unsigned int*)l, 16, 0, 0);
}

// ---------------- W1 transpose + cvt: src[e][256 i][512 h] -> dst[e][512 h][256 i]
__global__ __launch_bounds__(256) void transpose_cvt(const float* __restrict__ src,
                                                     unsigned short* __restrict__ dst,
                                                     int R, int C){
  __shared__ float t[32][33];
  int e = blockIdx.z, r0 = blockIdx.y * 32, c0 = blockIdx.x * 32;
  int lx = threadIdx.x & 31, ly = threadIdx.x >> 5;
  const float* s = src + (size_t)e * R * C;
  unsigned short* d = dst + (size_t)e * R * C;
#pragma unroll
  for (int i = 0; i < 4; i++){ int r = ly + i * 8; t[r][lx] = s[(size_t)(r0 + r) * C + c0 + lx]; }
  __syncthreads();
#pragma unroll
  for (int i = 0; i < 4; i++){ int r = ly + i * 8; d[(size_t)(c0 + r) * R + r0 + lx] = f2bf(t[lx][r]); }
}

// ---------------- W2 transpose + cvt into chunk-major: src[e][512 h][256 o] -> dst[e][16][256 o][32 h]
__global__ __launch_bounds__(256) void transpose_cvt_w2(const float* __restrict__ src,
                                                        unsigned short* __restrict__ dst){
  __shared__ float t[32][33];
  int e = blockIdx.z, r0 = blockIdx.y * 32, c0 = blockIdx.x * 32;   // r0 over h, c0 over o
  int lx = threadIdx.x & 31, ly = threadIdx.x >> 5;
  const float* s = src + (size_t)e * DHID * DOUT;
  unsigned short* d = dst + (size_t)e * DHID * DOUT + (r0 >> 5) * (DOUT * CH);
#pragma unroll
  for (int i = 0; i < 4; i++){ int r = ly + i * 8; t[r][lx] = s[(size_t)(r0 + r) * DOUT + c0 + lx]; }
  __syncthreads();
#pragma unroll
  for (int i = 0; i < 4; i++){ int rr = ly + i * 8; d[(size_t)(c0 + rr) * CH + lx] = f2bf(t[lx][rr]); }
}

// ---------------- gating: 512 blocks x 64 tokens; LDS-aggregated histogram
__global__ __launch_bounds__(256) void gating_kernel(const float* __restrict__ x,
                                                     const float* __restrict__ Wg,
                                                     const float* __restrict__ bg,
                                                     unsigned short* __restrict__ x_bf,
                                                     int* __restrict__ top_idx,
                                                     float* __restrict__ top_w,
                                                     int* __restrict__ counts){
  __shared__ float WgT[16][256];
  __shared__ int hist[16];
  int tid = threadIdx.x;
#pragma unroll
  for (int j = 0; j < 4; j++){
    float4 wv = *(const float4*)(Wg + tid * 16 + j * 4);
    WgT[j * 4 + 0][tid] = wv.x; WgT[j * 4 + 1][tid] = wv.y;
    WgT[j * 4 + 2][tid] = wv.z; WgT[j * 4 + 3][tid] = wv.w;
  }
  if (tid < 16) hist[tid] = 0;
  __syncthreads();
  int wid = tid >> 6, lane = tid & 63;

  for (int t = 0; t < 16; t++){
    int tok = blockIdx.x * 64 + wid * 16 + t;
    const float4 xv = *(const float4*)(x + (size_t)tok * DIN + lane * 4);
    ushort4 xb; xb.x = f2bf(xv.x); xb.y = f2bf(xv.y); xb.z = f2bf(xv.z); xb.w = f2bf(xv.w);
    *(ushort4*)(x_bf + (size_t)tok * DIN + lane * 4) = xb;
    float logit[16];
#pragma unroll
    for (int e = 0; e < 16; e++){
      const float4 wv = *(const float4*)(&WgT[e][lane * 4]);
      float v = xv.x * wv.x + xv.y * wv.y + xv.z * wv.z + xv.w * wv.w;
#pragma unroll
      for (int off = 32; off; off >>= 1) v += __shfl_xor(v, off, 64);
      logit[e] = v + bg[e];
    }
    if (lane == 0){
      int i1 = 0; float v1 = logit[0];
#pragma unroll
      for (int e = 1; e < 16; e++) if (logit[e] > v1){ v1 = logit[e]; i1 = e; }
      int i2 = -1; float v2 = -3.4e38f;
#pragma unroll
      for (int e = 0; e < 16; e++) if (e != i1 && logit[e] > v2){ v2 = logit[e]; i2 = e; }
      float tt = expf(v2 - v1);
      float w1 = 1.0f / (1.0f + tt);
      float w2 = tt / (1.0f + tt);
      top_idx[tok * 2] = i1; top_idx[tok * 2 + 1] = i2;
      top_w[tok * 2] = w1;  top_w[tok * 2 + 1] = w2;
      atomicAdd(&hist[i1], 1); atomicAdd(&hist[i2], 1);
    }
  }
  __syncthreads();
  if (tid < 16) atomicAdd(&counts[tid], hist[tid]);
}

// ---------------- prefix sum + XCD-affine block map (one wave)
__global__ void prefix_kernel(const int* __restrict__ counts, int* __restrict__ offsets,
                              int* __restrict__ cursor, int* __restrict__ bm_e,
                              int* __restrict__ bm_start, int* __restrict__ bm_end){
  int lane = threadIdx.x & 63;
  int c = (lane < 16) ? counts[lane] : 0;
  int s = c;
#pragma unroll
  for (int off = 1; off < 16; off <<= 1){ int o = __shfl_up(s, off, 64); if (lane >= off) s += o; }
  int start = s - c;
  if (lane < 16){ offsets[lane] = start; cursor[lane] = start; }
  int nb = (c + BM - 1) >> 7;
  int nb_partner = __shfl(nb, lane ^ 8, 64);
  if (lane < 8){
    int filled = nb + nb_partner;
    if (filled > SLOTS) filled = SLOTS;
    for (int i = filled; i < SLOTS; i++) bm_e[lane * SLOTS + i] = -1;
  }
  if (lane < 16){
    int sbase = (lane < 8) ? 0 : nb_partner;
    int xcd = lane & 7;
    for (int b = 0; b < nb; b++){
      int idx = xcd * SLOTS + sbase + b;
      if (sbase + b < SLOTS){
        bm_e[idx] = lane; bm_start[idx] = start + b * BM; bm_end[idx] = start + c;
      }
    }
  }
}

// ---------------- scatter: block-aggregated chunk reservation, LDS ranks
__global__ __launch_bounds__(256) void scatter_kernel(const int* __restrict__ top_idx,
                                                      const float* __restrict__ top_w,
                                                      int* __restrict__ cursor,
                                                      int* __restrict__ pair_tok,
                                                      float* __restrict__ pair_w,
                                                      int* __restrict__ pair_slot){
  __shared__ int hist[16], base[16], rank[16];
  int tid = threadIdx.x;
  if (tid < 16){ hist[tid] = 0; rank[tid] = 0; }
  __syncthreads();
  int t = blockIdx.x * 256 + tid;
  int e0 = top_idx[t * 2], e1 = top_idx[t * 2 + 1];
  float w0 = top_w[t * 2], w1 = top_w[t * 2 + 1];
  atomicAdd(&hist[e0], 1); atomicAdd(&hist[e1], 1);
  __syncthreads();
  if (tid < 16) base[tid] = atomicAdd(&cursor[tid], hist[tid]);
  __syncthreads();
  int r0 = atomicAdd(&rank[e0], 1);
  int p0 = base[e0] + r0;
  pair_tok[p0] = t; pair_w[p0] = w0; pair_slot[t * 2] = p0;
  int r1 = atomicAdd(&rank[e1], 1);
  int p1 = base[e1] + r1;
  pair_tok[p1] = t; pair_w[p1] = w1; pair_slot[t * 2 + 1] = p1;
}

// ---------------- fused 2-layer expert MLP: 128 pairs/block, 8 waves (4mg x 2ng)
// M=32/wave, N split across ng -> each W read feeds 2 MFMAs with acc only 64
// regs (no spill). chunk=32, dbuf W staging, shared h tile + mid barrier.
// 74KB LDS -> 2 blocks/CU (16 waves of TLP). b1 preloaded to LDS.
__global__ __launch_bounds__(512, 1) void moe_gemm_kernel(
    const unsigned short* __restrict__ x_bf,   // [B][256]
    const unsigned short* __restrict__ W1t,    // [E][512 h][256 i]
    const unsigned short* __restrict__ W2c,    // [E][16 c][256 o][32 h]
    const float* __restrict__ b1,              // [E][512]
    const float* __restrict__ b2,              // [E][256]
    const int* __restrict__ pair_tok, const float* __restrict__ pair_w,
    const int* __restrict__ bm_e, const int* __restrict__ bm_start,
    const int* __restrict__ bm_end,
    unsigned short* __restrict__ ypair){       // [65536][256] bf16
  int xcd = blockIdx.x & 7, slot = blockIdx.x >> 3;
  int bmi = xcd * SLOTS + slot;
  int e = bm_e[bmi];
  if (e < 0) return;
  int rs = bm_start[bmi], re = bm_end[bmi];

  __shared__ unsigned short w1s[2][CH * 256];   // 2x16KB [h row][i], 512B rows, XOR(bits4-6)
  __shared__ unsigned short w2s[2][256 * CH];   // 2x16KB [o row][h], row-pair 128B XOR
  __shared__ unsigned short hs[BM * CH];        // 8KB [m 128][h 32], row-pair 128B XOR
  __shared__ float b1s[DHID];                   // 2KB
  char* hsb = (char*)hs;

  int tid = threadIdx.x, wid = tid >> 6, lane = tid & 63, lr = lane & 15, lh = lane >> 4;
  int mg = wid >> 1, ng = wid & 1;
  const char* gW1 = (const char*)(W1t + (size_t)e * DHID * DIN);
  const char* gW2 = (const char*)(W2c + (size_t)e * DOUT * DHID);

  b1s[tid] = b1[e * DHID + tid];

  // ---- per-lane loop-invariant staging source offsets (pre-swizzled)
  int o1[2], o2[2];
#pragma unroll
  for (int k = 0; k < 2; k++){
    int g = k * 512 + tid;              // 16B granule index, 0..1023 (16KB tile)
    int r = g >> 5;                     // w1: row (512B = 32 granules)
    o1[k] = r * 512 + ((g & 31) ^ (r & 7)) * 16;
    int p = g >> 3;                     // w2: row-pair (128B = 8 granules)
    int q = (g & 7) ^ (p & 7);
    int n = p * 2 + (q >> 2), sgr = q & 3;
    o2[k] = n * 64 + sgr * 16;
  }

  // ---- x rows (2 per lane: m-tiles of this wave's 32-row band) -> registers
  bf16x8 xr[2][8];
#pragma unroll
  for (int m = 0; m < 2; m++){
    int g0 = rs + 32 * mg + m * 16 + lr;
    int gc = g0 < re ? g0 : (re - 1);
    int tok = pair_tok[gc];
    const unsigned short* xrow = x_bf + (size_t)tok * DIN + lh * 8;
#pragma unroll
    for (int ks = 0; ks < 8; ks++) xr[m][ks] = *(const bf16x8*)(xrow + ks * 32);
  }

#define STAGE(c, sl) {                                                    \
    const char* s1 = gW1 + (size_t)(c) * 16384;                           \
    const char* s2 = gW2 + (size_t)(c) * 16384;                           \
    char* d1 = (char*)w1s[sl]; char* d2 = (char*)w2s[sl];                 \
    _Pragma("unroll")                                                     \
    for (int k = 0; k < 2; k++){                                          \
      gload16(s1 + o1[k], d1 + k * 8192 + wid * 1024);                    \
      gload16(s2 + o2[k], d2 + k * 8192 + wid * 1024);                    \
    } }

  f32x4 acc[2][8];
#pragma unroll
  for (int m = 0; m < 2; m++)
#pragma unroll
    for (int i = 0; i < 8; i++) acc[m][i] = (f32x4){0.f, 0.f, 0.f, 0.f};

  STAGE(0, 0);
  __syncthreads();                       // chunk-0 staged

  for (int c = 0; c < NCH; c++){
    int sl = c & 1;
    if (c + 1 < NCH) STAGE(c + 1, sl ^ 1);   // in flight under phase A

    // ---- phase A: h[32 rows of mg][16 hid of ng] ; each W1 read feeds 2 MFMAs
    const char* w1b = (const char*)w1s[sl];
    f32x4 hacc[2];
    hacc[0] = (f32x4){0.f, 0.f, 0.f, 0.f};
    hacc[1] = (f32x4){0.f, 0.f, 0.f, 0.f};
    int hrow = 16 * ng + lr;                   // hid-local 0..31
#pragma unroll
    for (int ks = 0; ks < 8; ks++){
      bf16x8 b = *(const bf16x8*)(w1b + ((hrow * 512 + ks * 64 + lh * 16) ^ ((hrow & 7) << 4)));
      hacc[0] = __builtin_amdgcn_mfma_f32_16x16x32_bf16(xr[0][ks], b, hacc[0], 0, 0, 0);
      hacc[1] = __builtin_amdgcn_mfma_f32_16x16x32_bf16(xr[1][ks], b, hacc[1], 0, 0, 0);
    }

    // ---- relu(h+b1) -> shared hs (row-pair XOR layout)
    {
      float b1v = b1s[c * CH + 16 * ng + lr];
      int col2 = (16 * ng + lr) * 2;
#pragma unroll
      for (int m = 0; m < 2; m++)
#pragma unroll
        for (int r = 0; r < 4; r++){
          int mm = 32 * mg + m * 16 + lh * 4 + r;
          float v = fmaxf(hacc[m][r] + b1v, 0.f);
          int adr = (mm >> 1) * 128 + ((((mm & 1) << 6) + col2) ^ (((mm >> 1) & 7) << 4));
          *(unsigned short*)(hsb + adr) = f2bf(v);
        }
    }
    __syncthreads();                     // h tile complete (both ng halves)

    // ---- phase B: y[32 rows of mg][128 cols of ng] ; each W2 read feeds 2 MFMAs
    bf16x8 ha[2];
#pragma unroll
    for (int m = 0; m < 2; m++){
      int mm = 32 * mg + m * 16 + lr;
      int hadr = (mm >> 1) * 128 + ((((mm & 1) << 6) + (lh << 4)) ^ (((mm >> 1) & 7) << 4));
      ha[m] = *(const bf16x8*)(hsb + hadr);
    }
    const char* w2b = (const char*)w2s[sl];
#pragma unroll
    for (int nt = 0; nt < 8; nt++){
      int n = 128 * ng + nt * 16 + lr;
      int adr = (n >> 1) * 128 + ((((n & 1) << 6) + (lh << 4)) ^ (((n >> 1) & 7) << 4));
      bf16x8 b = *(const bf16x8*)(w2b + adr);
      acc[0][nt] = __builtin_amdgcn_mfma_f32_16x16x32_bf16(ha[0], b, acc[0][nt], 0, 0, 0);
      acc[1][nt] = __builtin_amdgcn_mfma_f32_16x16x32_bf16(ha[1], b, acc[1][nt], 0, 0, 0);
    }
    __syncthreads();   // staged chunk c+1 ready; hs/W-slot reads complete
  }

  // ---- epilogue: fold gate weight + b2, store per-pair bf16 rows
#pragma unroll
  for (int m = 0; m < 2; m++){
    float wrow[4]; int grow[4];
#pragma unroll
    for (int r = 0; r < 4; r++){
      int gg = rs + 32 * mg + m * 16 + lh * 4 + r;
      grow[r] = gg;
      wrow[r] = (gg < re) ? pair_w[gg] : 0.f;
    }
#pragma unroll
    for (int nt = 0; nt < 8; nt++){
      int col = 128 * ng + nt * 16 + lr;
      float b2v = b2[e * DOUT + col];
#pragma unroll
      for (int r = 0; r < 4; r++){
        if (grow[r] < re)
          ypair[(size_t)grow[r] * DOUT + col] = f2bf(wrow[r] * (acc[m][nt][r] + b2v));
      }
    }
  }
#undef STAGE
}

// ---------------- combine two pair rows per token
__global__ __launch_bounds__(256) void combine_kernel(const unsigned short* __restrict__ yp,
                                                      const int* __restrict__ pair_slot,
                                                      float* __restrict__ out){
  int idx = blockIdx.x * 256 + threadIdx.x;
  int t = idx >> 6;
  int c4 = (idx & 63) << 2;
  int s0 = pair_slot[t * 2], s1 = pair_slot[t * 2 + 1];
  ushort4 a = *(const ushort4*)(yp + (size_t)s0 * DOUT + c4);
  ushort4 b = *(const ushort4*)(yp + (size_t)s1 * DOUT + c4);
  float4 o;
  o.x = bf2f(a.x) + bf2f(b.x);
  o.y = bf2f(a.y) + bf2f(b.y);
  o.z = bf2f(a.z) + bf2f(b.z);
  o.w = bf2f(a.w) + bf2f(b.w);
  *(float4*)(out + (size_t)t * DOUT + c4) = o;
}

extern "C" void kernel_launch(void* const* d_in, const int* in_sizes, int n_in,
                              void* d_out, int out_size, void* d_ws, size_t ws_size,
                              hipStream_t stream){
  (void)in_sizes; (void)n_in; (void)out_size; (void)ws_size;
  const float* x  = (const float*)d_in[0];
  const float* Wg = (const float*)d_in[1];
  const float* bg = (const float*)d_in[2];
  const float* W1 = (const float*)d_in[3];
  const float* b1 = (const float*)d_in[4];
  const float* W2 = (const float*)d_in[5];
  const float* b2 = (const float*)d_in[6];
  float* out = (float*)d_out;
  char* ws = (char*)d_ws;

  unsigned short* x_bf  = (unsigned short*)(ws);                 // 16,777,216
  unsigned short* W1t   = (unsigned short*)(ws + 16777216);      //  4,194,304
  unsigned short* W2ck  = (unsigned short*)(ws + 20971520);      //  4,194,304
  unsigned short* ypair = (unsigned short*)(ws + 25165824);      // 33,554,432
  int*   top_idx  = (int*)  (ws + 58720256);
  float* top_w    = (float*)(ws + 58982400);
  int*   pair_tok = (int*)  (ws + 59244544);
  float* pair_w   = (float*)(ws + 59506688);
  int*   pair_slot= (int*)  (ws + 59768832);
  int*   counts   = (int*)  (ws + 60030976);
  int*   offsets  = (int*)  (ws + 60031040);
  int*   cursor   = (int*)  (ws + 60031104);
  int*   bm_e     = (int*)  (ws + 60031232);   // 768 ints
  int*   bm_start = (int*)  (ws + 60036608);   // 768 ints
  int*   bm_end   = (int*)  (ws + 60041984);   // 768 ints

  hipMemsetAsync(counts, 0, 64, stream);
  transpose_cvt<<<dim3(16, 8, 16), 256, 0, stream>>>(W1, W1t, 256, 512);
  transpose_cvt_w2<<<dim3(8, 16, 16), 256, 0, stream>>>(W2, W2ck);
  gating_kernel<<<512, 256, 0, stream>>>(x, Wg, bg, x_bf, top_idx, top_w, counts);
  prefix_kernel<<<1, 64, 0, stream>>>(counts, offsets, cursor, bm_e, bm_start, bm_end);
  scatter_kernel<<<128, 256, 0, stream>>>(top_idx, top_w, cursor, pair_tok, pair_w, pair_slot);
  moe_gemm_kernel<<<8 * SLOTS, 512, 0, stream>>>(x_bf, W1t, W2ck, b1, b2, pair_tok, pair_w,
                                                 bm_e, bm_start, bm_end, ypair);
  combine_kernel<<<8192, 256, 0, stream>>>(ypair, pair_slot, out);
}